// Round 3
// baseline (58.414 us; speedup 1.0000x reference)
//
#include <hip/hip_runtime.h>

// MultiLIF forward: B=32, L=1024, K=512. 16384 chains (b,k), serial over t.
// Outputs concat: [spikes | series | v_seq], each B*L*K f32.
//
// Numerics (validated r1-r6): pass = zero spike flips + small v drift.
// Fused updates: v<-fma(v,.95,I), a<-fma(a,.99,s), th<-fma(1.5,a,1.5);
// s == s_hard exactly; reset = (fire ? -0.5 : v); snum exact int accum.
//
// r9 structure: producer/consumer. Per 64-chain group (1 block, 448 thr):
//   wave 0   = loader: streams I into a 32KB LDS ring (8 slabs x 16 steps
//              x 64 chains x 4B), reg-staged float4 loads 8 slabs ahead
//              (~4us of latency cover), ds_write_b128. vmcnt = loads only.
//   waves1-6 = consumers (3 streams x 2 store-parities, r6's proven
//              template discipline): read It via ds_read_b32 (lgkmcnt),
//              nontemporal stores NEVER vmcnt-waited.
// This removes the load<->store vmcnt coupling that r7/r8 showed is the
// limiter (vmcnt retires in issue order; any consume-wait in a mixed
// stream drains all older stores; r8 additionally hit the 63-outstanding
// vmcnt cap). Sync = raw s_barrier per slab (NOT __syncthreads: that
// emits vmcnt(0) and would drain consumer stores). Loader fences
// lgkmcnt(0) before each barrier; empty memory-clobber asm after each
// barrier pins LDS ops on the correct side. All other ordering pairs
// have >=6 barriers of ring slack.

namespace {
constexpr int kL = 1024;
constexpr int kK = 512;
constexpr size_t kN = (size_t)32 * kL * kK;      // per-output elements
constexpr float kVD = 1.0f - 1.0f / 20.0f;       // 0.95f
constexpr float kAD = 1.0f - 1.0f / 100.0f;      // 0.99f
constexpr int kSlabSteps = 16;                   // t-steps per slab
constexpr int kRing = 8;                         // slabs resident in LDS
constexpr int kSlabFloats = kSlabSteps * 64;     // 1024 floats = 4KB
}

// ---- loader: issue one slab's 4 x float4 loads (lane covers 4 t x 4 k) ----
__device__ __forceinline__ void issue_slab(const float* __restrict__ gq,
                                           float4 (&r)[4]) {
#pragma unroll
    for (int q = 0; q < 4; ++q)
        r[q] = *reinterpret_cast<const float4*>(gq + (size_t)q * 4 * kK);
}

// ---- loader: commit one slab from regs to LDS ring slot (linear [t][k]) ----
__device__ __forceinline__ void write_slab(float* __restrict__ ring, int slot,
                                           int lane, const float4 (&r)[4]) {
    float* b = ring + (slot << 10) + (lane << 2);
#pragma unroll
    for (int q = 0; q < 4; ++q)
        *reinterpret_cast<float4*>(b + (q << 8)) = r[q];
}

__device__ __forceinline__ void run_loader(const float* __restrict__ gp,
                                           float* __restrict__ ring,
                                           const int lane) {
    float4 rr[kRing][4];   // statically indexed only (rule #20)
    // prologue: issue slabs 0..7, commit slab 0
#pragma unroll
    for (int k = 0; k < 8; ++k)
        issue_slab(gp + (size_t)k * kSlabSteps * kK, rr[k]);
    write_slab(ring, 0, lane, rr[0]);
    asm volatile("s_waitcnt lgkmcnt(0)" ::: "memory");
    // main: at iter s (=8c+k): barrier(s); issue slab s+8 -> rr[s&7];
    // commit slab s+1 (issued 7 iters ago) from rr[(s+1)&7]; lgkm fence.
#pragma unroll 1
    for (int c = 0; c < 7; ++c) {
#pragma unroll
        for (int k = 0; k < 8; ++k) {
            const int s = c * 8 + k;
            __builtin_amdgcn_s_barrier();
            asm volatile("" ::: "memory");
            issue_slab(gp + (size_t)(s + 8) * kSlabSteps * kK, rr[k]);
            write_slab(ring, (k + 1) & 7, lane, rr[(k + 1) & 7]);
            asm volatile("s_waitcnt lgkmcnt(0)" ::: "memory");
        }
    }
    // epilogue: s = 56..63, commit slabs 57..63, no new issues
#pragma unroll
    for (int k = 0; k < 8; ++k) {
        __builtin_amdgcn_s_barrier();
        asm volatile("" ::: "memory");
        if (k < 7) {
            write_slab(ring, (k + 1) & 7, lane, rr[(k + 1) & 7]);
            asm volatile("s_waitcnt lgkmcnt(0)" ::: "memory");
        }
    }
}

// ---- consumer: one slab. W: 0=spikes,1=series,2=v. STORE: store parity. ----
template <int W, bool STORE>
__device__ __forceinline__ void eat_slab(const float* __restrict__ ring,
                                         const int slot, const int lane,
                                         float* __restrict__ outp,
                                         unsigned& off, float& v, float& a,
                                         float& snum, float& th) {
    __builtin_amdgcn_s_barrier();
    asm volatile("" ::: "memory");       // pin ds_reads after the barrier
    const float* rb = ring + (slot << 10) + lane;
    float ib[16];
#pragma unroll
    for (int j = 0; j < 16; ++j) ib[j] = rb[j << 6];   // 2 lanes/bank: free
#pragma unroll
    for (int j = 0; j < 16; ++j) {
        const float It = ib[j];
        v = __fmaf_rn(v, kVD, It);                     // leak + input
        const bool fire = (v >= th);
        const float s = fire ? 1.0f : 0.0f;
        snum += s;                                     // exact int accum
        if (STORE) {
            const float val = (W == 0) ? s : (W == 1) ? snum : v;
            __builtin_nontemporal_store(val, outp + off);
        }
        v = fire ? -0.5f : v;                          // exact reset
        a = __fmaf_rn(a, kAD, s);
        th = __fmaf_rn(1.5f, a, 1.5f);
        off += kK;
    }
}

template <int W, int PAR>
__device__ __forceinline__ void run_consumer(const float* __restrict__ ring,
                                             const int lane,
                                             float* __restrict__ outp) {
    float v = 0.0f, a = 0.0f, snum = 0.0f, th = 1.5f;
    unsigned off = 0;
#pragma unroll 1
    for (int p = 0; p < 32; ++p) {
        eat_slab<W, PAR == 0>(ring, (2 * p) & 7, lane, outp, off, v, a, snum, th);
        eat_slab<W, PAR == 1>(ring, (2 * p + 1) & 7, lane, outp, off, v, a, snum, th);
    }
}

__global__ __launch_bounds__(448, 2) void multilif_fwd(
        const float* __restrict__ I, float* __restrict__ out) {
    __shared__ __align__(16) float ring[kRing * kSlabFloats];   // 32 KB
    const int lane = (int)threadIdx.x & 63;
    const int w = (int)threadIdx.x >> 6;             // 0 = loader, 1..6 cons.
    const int wb0 = (int)blockIdx.x * 64;            // first chain of group
    const size_t cb = (size_t)(wb0 >> 9) * ((size_t)kL * kK)
                    + (size_t)(wb0 & (kK - 1));

    if (w == 0) {
        // lane covers t_off = lane>>4 (0..3), k_off = (lane&15)*4 (x4 floats)
        const float* gp = I + cb + (size_t)(lane >> 4) * kK
                        + (size_t)((lane & 15) << 2);
        run_loader(gp, ring, lane);
        return;
    }
    const int cw = w - 1;                            // 0..5
    float* outp = out + (size_t)(cw >> 1) * kN + cb + (size_t)lane;
    switch (cw) {
        case 0: run_consumer<0, 0>(ring, lane, outp); break;  // spikes even
        case 1: run_consumer<0, 1>(ring, lane, outp); break;  // spikes odd
        case 2: run_consumer<1, 0>(ring, lane, outp); break;  // series even
        case 3: run_consumer<1, 1>(ring, lane, outp); break;  // series odd
        case 4: run_consumer<2, 0>(ring, lane, outp); break;  // v_seq even
        default: run_consumer<2, 1>(ring, lane, outp); break; // v_seq odd
    }
}

extern "C" void kernel_launch(void* const* d_in, const int* in_sizes, int n_in,
                              void* d_out, int out_size, void* d_ws, size_t ws_size,
                              hipStream_t stream) {
    const float* I = (const float*)d_in[0];
    float* out = (float*)d_out;
    // 256 chain-groups x (1 loader + 6 consumer) waves = 256 blocks x 448 thr.
    dim3 grid((32 * kK) / 64), block(448);
    hipLaunchKernelGGL(multilif_fwd, grid, block, 0, stream, I, out);
}

// Round 4
// 46.734 us; speedup vs baseline: 1.2499x; 1.2499x over previous
//
#include <hip/hip_runtime.h>

// MultiLIF forward: B=32, L=1024, K=512. 16384 chains (b,k), serial over t.
// Outputs concat: [spikes | series | v_seq], each B*L*K f32.
//
// Numerics (validated r1-r6): pass = zero spike flips + small v drift.
// Fused updates: v<-fma(v,.95,I), a<-fma(a,.99,s), th<-fma(1.5,a,1.5);
// s == s_hard exactly; reset = (fire ? -0.5 : v); snum exact int accum.
//
// r10 structure: producer/consumer with DMA staging. Per 64-chain group
// (1 block, 448 thr):
//   wave 0   = loader: global_load_lds (dwordx4) into a 32KB LDS ring
//              (8 slabs x 16 steps x 64 chains x 4B), hand-counted vmcnt
//              (24 steady / 24..0 tail), 7 slabs (~4.5us) of lead held in
//              the DMA queue -- ZERO register footprint, so the compiler
//              cannot collapse the pipeline (r9 failed because reg-staged
//              rr[7][4] needed 112 VGPRs across barriers; VGPR_Count=40
//              proved the compiler spilled it -> 64 serialized HBM misses
//              = 58us). vmcnt stream = loads only.
//   waves1-6 = consumers (3 streams x 2 store-parities, r6's template
//              discipline): ds_read_b32 from ring (2 lanes/bank = free),
//              nontemporal stores NEVER vmcnt-waited.
// Sync = raw s_barrier per slab (NOT __syncthreads: that emits vmcnt(0)
// and would drain consumer stores / loader DMA lead). asm memory clobber
// after each barrier pins LDS ops on the correct side.
// Ring slot math: at period s loader fills slot (s+7)&7 = (s-1)&7, which
// consumers finished reading before barrier #s. No WAR.

namespace {
constexpr int kL = 1024;
constexpr int kK = 512;
constexpr size_t kN = (size_t)32 * kL * kK;      // per-output elements
constexpr float kVD = 1.0f - 1.0f / 20.0f;       // 0.95f
constexpr float kAD = 1.0f - 1.0f / 100.0f;      // 0.99f
constexpr int kSlabSteps = 16;                   // t-steps per slab
constexpr int kRing = 8;                         // slabs resident in LDS
constexpr int kSlabFloats = kSlabSteps * 64;     // 1024 floats = 4KB
}

template <int N>
__device__ __forceinline__ void wait_vmcnt() {
    if constexpr (N == 0)       asm volatile("s_waitcnt vmcnt(0)" ::: "memory");
    else if constexpr (N == 4)  asm volatile("s_waitcnt vmcnt(4)" ::: "memory");
    else if constexpr (N == 8)  asm volatile("s_waitcnt vmcnt(8)" ::: "memory");
    else if constexpr (N == 12) asm volatile("s_waitcnt vmcnt(12)" ::: "memory");
    else if constexpr (N == 16) asm volatile("s_waitcnt vmcnt(16)" ::: "memory");
    else if constexpr (N == 20) asm volatile("s_waitcnt vmcnt(20)" ::: "memory");
    else                        asm volatile("s_waitcnt vmcnt(24)" ::: "memory");
}

// One DMA instruction: 64 lanes x 16B -> 1KB contiguous LDS at uniform base.
__device__ __forceinline__ void gload_lds16(const float* g, float* l) {
    __builtin_amdgcn_global_load_lds(
        (const __attribute__((address_space(1))) void*)g,
        (__attribute__((address_space(3))) void*)l, 16, 0, 0);
}

// Issue one slab (4KB = 4 DMA ops). gsrc already carries the per-lane
// offset (t_off = lane>>4, k_off = (lane&15)*4) matching the DMA's
// fixed LDS layout (base + lane*16B), so LDS ends up linear [t][k].
__device__ __forceinline__ void issue_dma(const float* __restrict__ gsrc,
                                          float* __restrict__ ring,
                                          const int slab, const int slot) {
    const float* gs = gsrc + (size_t)(slab * kSlabSteps) * kK;
    float* ls = ring + (slot << 10);
#pragma unroll
    for (int q = 0; q < 4; ++q)
        gload_lds16(gs + (size_t)(q * 4) * kK, ls + (q << 8));
}

__device__ __forceinline__ void run_loader(const float* __restrict__ gsrc,
                                           float* __restrict__ ring) {
    // prologue: issue slabs 0..6 -> 28 loads in flight
#pragma unroll
    for (int s = 0; s < 7; ++s) issue_dma(gsrc, ring, s, s);
    // main: periods 0..56. wait(24) retires the oldest slab (slab s);
    // barrier releases consumers into slab s; refill slot (s+7)&7.
#pragma unroll 1
    for (int s = 0; s < 57; ++s) {
        wait_vmcnt<24>();
        __builtin_amdgcn_s_barrier();
        asm volatile("" ::: "memory");
        issue_dma(gsrc, ring, s + 7, (s + 7) & 7);
    }
    // tail: periods 57..63, drain 24 -> 0, no new issues
    wait_vmcnt<24>(); __builtin_amdgcn_s_barrier();
    wait_vmcnt<20>(); __builtin_amdgcn_s_barrier();
    wait_vmcnt<16>(); __builtin_amdgcn_s_barrier();
    wait_vmcnt<12>(); __builtin_amdgcn_s_barrier();
    wait_vmcnt<8>();  __builtin_amdgcn_s_barrier();
    wait_vmcnt<4>();  __builtin_amdgcn_s_barrier();
    wait_vmcnt<0>();  __builtin_amdgcn_s_barrier();
}

// ---- consumer: one slab. W: 0=spikes,1=series,2=v. STORE: store parity. ----
template <int W, bool STORE>
__device__ __forceinline__ void eat_slab(const float* __restrict__ ring,
                                         const int slot, const int lane,
                                         float* __restrict__ outp,
                                         unsigned& off, float& v, float& a,
                                         float& snum, float& th) {
    __builtin_amdgcn_s_barrier();
    asm volatile("" ::: "memory");       // pin ds_reads after the barrier
    const float* rb = ring + (slot << 10) + lane;
    float ib[16];
#pragma unroll
    for (int j = 0; j < 16; ++j) ib[j] = rb[j << 6];   // 2 lanes/bank: free
#pragma unroll
    for (int j = 0; j < 16; ++j) {
        const float It = ib[j];
        v = __fmaf_rn(v, kVD, It);                     // leak + input
        const bool fire = (v >= th);
        const float s = fire ? 1.0f : 0.0f;
        snum += s;                                     // exact int accum
        if (STORE) {
            const float val = (W == 0) ? s : (W == 1) ? snum : v;
            __builtin_nontemporal_store(val, outp + off);
        }
        v = fire ? -0.5f : v;                          // exact reset
        a = __fmaf_rn(a, kAD, s);
        th = __fmaf_rn(1.5f, a, 1.5f);
        off += kK;
    }
}

template <int W, int PAR>
__device__ __forceinline__ void run_consumer(const float* __restrict__ ring,
                                             const int lane,
                                             float* __restrict__ outp) {
    float v = 0.0f, a = 0.0f, snum = 0.0f, th = 1.5f;
    unsigned off = 0;
#pragma unroll 1
    for (int p = 0; p < 32; ++p) {
        eat_slab<W, PAR == 0>(ring, (2 * p) & 7, lane, outp, off, v, a, snum, th);
        eat_slab<W, PAR == 1>(ring, (2 * p + 1) & 7, lane, outp, off, v, a, snum, th);
    }
}

__global__ __launch_bounds__(448) void multilif_fwd(
        const float* __restrict__ I, float* __restrict__ out) {
    __shared__ __align__(16) float ring[kRing * kSlabFloats];   // 32 KB
    const int lane = (int)threadIdx.x & 63;
    const int w = (int)threadIdx.x >> 6;             // 0 = loader, 1..6 cons.
    const int wb0 = (int)blockIdx.x * 64;            // first chain of group
    const size_t cb = (size_t)(wb0 >> 9) * ((size_t)kL * kK)
                    + (size_t)(wb0 & (kK - 1));

    if (w == 0) {
        // per-lane source offset matching DMA LDS layout (lane*16B):
        // t_off = lane>>4 (0..3), k_off = (lane&15)*4
        const float* gsrc = I + cb + (size_t)(lane >> 4) * kK
                          + (size_t)((lane & 15) << 2);
        run_loader(gsrc, ring);
        return;
    }
    const int cw = w - 1;                            // 0..5
    float* outp = out + (size_t)(cw >> 1) * kN + cb + (size_t)lane;
    switch (cw) {
        case 0: run_consumer<0, 0>(ring, lane, outp); break;  // spikes even
        case 1: run_consumer<0, 1>(ring, lane, outp); break;  // spikes odd
        case 2: run_consumer<1, 0>(ring, lane, outp); break;  // series even
        case 3: run_consumer<1, 1>(ring, lane, outp); break;  // series odd
        case 4: run_consumer<2, 0>(ring, lane, outp); break;  // v_seq even
        default: run_consumer<2, 1>(ring, lane, outp); break; // v_seq odd
    }
}

extern "C" void kernel_launch(void* const* d_in, const int* in_sizes, int n_in,
                              void* d_out, int out_size, void* d_ws, size_t ws_size,
                              hipStream_t stream) {
    const float* I = (const float*)d_in[0];
    float* out = (float*)d_out;
    // 256 chain-groups x (1 loader + 6 consumer) waves = 256 blocks x 448 thr.
    dim3 grid((32 * kK) / 64), block(448);
    hipLaunchKernelGGL(multilif_fwd, grid, block, 0, stream, I, out);
}

// Round 5
// 42.257 us; speedup vs baseline: 1.3824x; 1.1059x over previous
//
#include <hip/hip_runtime.h>

// MultiLIF forward: B=32, L=1024, K=512. 16384 chains (b,k), serial over t.
// Outputs concat: [spikes | series | v_seq], each B*L*K f32.
//
// Numerics (validated r1-r6): pass = zero spike flips + small v drift.
// Fused updates: v<-fma(v,.95,I), a<-fma(a,.99,s), th<-fma(1.5,a,1.5);
// s == s_hard exactly; reset = (fire ? -0.5 : v); snum exact int accum.
//
// r11 = r10 (best known, 46.7us) with HALVED sync frequency: barrier every
// 2 slabs (32 barriers) instead of every slab (64). r10's residual vs the
// 6.3 TB/s mixed floor (44.2us for 278MB) is ~5%; theory: 64 lockstep
// barriers x ~50-100ns of 7-wave skew (store-issue bursts) = 2-5us. Two
// slabs of straightline runway per sync also lets the compiler overlap
// slab-A stores with slab-B ds_reads.
//
// Structure (per 64-chain group, 1 block, 448 thr):
//   wave 0   = loader: global_load_lds dwordx4 into 32KB LDS ring (8 slabs
//              x 16 steps x 64 chains x 4B). Prologue issues 6 slabs
//              (24 DMA); per period: vmcnt(16) [2 oldest slabs landed] ->
//              s_barrier -> issue 2 slabs (back to 24 in flight, lead
//              4-6 slabs ~3us >> 900ns HBM). vmcnt stream = loads only,
//              zero register footprint (r9: reg staging spilled, 58us).
//   waves1-6 = consumers (3 streams x 2 store-parities, template-
//              specialized straightline slabs -- r7 showed runtime
//              store/no-store joins force conservative vmcnt waits):
//              ds_read_b32 from ring (2 lanes/bank = free), nontemporal
//              stores NEVER vmcnt-waited (r7/r8: any consume-wait in a
//              mixed vmcnt stream drains all older stores).
// Sync = raw s_barrier (NOT __syncthreads: emits vmcnt(0), would drain
// consumer stores / DMA lead). asm memory clobber pins LDS ops.
// Ring math: period p consumers read slots (2p)&7,(2p+1)&7; loader fills
// (2p+6)&7=(2p-2)&7,(2p+7)&7=(2p-1)&7 -- read in period p-1, done before
// barrier p. No WAR. Max outstanding DMA 24 < 63 cap.

namespace {
constexpr int kL = 1024;
constexpr int kK = 512;
constexpr size_t kN = (size_t)32 * kL * kK;      // per-output elements
constexpr float kVD = 1.0f - 1.0f / 20.0f;       // 0.95f
constexpr float kAD = 1.0f - 1.0f / 100.0f;      // 0.99f
constexpr int kSlabSteps = 16;                   // t-steps per slab
constexpr int kRing = 8;                         // slabs resident in LDS
constexpr int kSlabFloats = kSlabSteps * 64;     // 1024 floats = 4KB
}

template <int N>
__device__ __forceinline__ void wait_vmcnt() {
    if constexpr (N == 0)       asm volatile("s_waitcnt vmcnt(0)" ::: "memory");
    else if constexpr (N == 8)  asm volatile("s_waitcnt vmcnt(8)" ::: "memory");
    else                        asm volatile("s_waitcnt vmcnt(16)" ::: "memory");
}

// One DMA instruction: 64 lanes x 16B -> 1KB contiguous LDS at uniform base.
__device__ __forceinline__ void gload_lds16(const float* g, float* l) {
    __builtin_amdgcn_global_load_lds(
        (const __attribute__((address_space(1))) void*)g,
        (__attribute__((address_space(3))) void*)l, 16, 0, 0);
}

// Issue one slab (4KB = 4 DMA ops). gsrc already carries the per-lane
// offset (t_off = lane>>4, k_off = (lane&15)*4) matching the DMA's
// fixed LDS layout (base + lane*16B), so LDS ends up linear [t][k].
__device__ __forceinline__ void issue_dma(const float* __restrict__ gsrc,
                                          float* __restrict__ ring,
                                          const int slab, const int slot) {
    const float* gs = gsrc + (size_t)(slab * kSlabSteps) * kK;
    float* ls = ring + (slot << 10);
#pragma unroll
    for (int q = 0; q < 4; ++q)
        gload_lds16(gs + (size_t)(q * 4) * kK, ls + (q << 8));
}

__device__ __forceinline__ void run_loader(const float* __restrict__ gsrc,
                                           float* __restrict__ ring) {
    // prologue: issue slabs 0..5 -> 24 loads in flight
#pragma unroll
    for (int s = 0; s < 6; ++s) issue_dma(gsrc, ring, s, s);
    // main periods 0..28: vmcnt(16) retires 2 oldest slabs (2p, 2p+1);
    // barrier releases consumers into them; refill 2 slabs.
#pragma unroll 1
    for (int p = 0; p < 29; ++p) {
        wait_vmcnt<16>();
        __builtin_amdgcn_s_barrier();
        asm volatile("" ::: "memory");
        issue_dma(gsrc, ring, 2 * p + 6, (2 * p + 6) & 7);
        issue_dma(gsrc, ring, 2 * p + 7, (2 * p + 7) & 7);
    }
    // drain periods 29..31 (slabs 58..63), no new issues
    wait_vmcnt<16>(); __builtin_amdgcn_s_barrier();   // slabs 58,59 ready
    wait_vmcnt<8>();  __builtin_amdgcn_s_barrier();   // slabs 60,61 ready
    wait_vmcnt<0>();  __builtin_amdgcn_s_barrier();   // slabs 62,63 ready
}

// ---- consumer: one slab, no barrier inside. W: 0=spikes,1=series,2=v. ----
template <int W, bool STORE>
__device__ __forceinline__ void eat_slab(const float* __restrict__ ring,
                                         const int slot, const int lane,
                                         float* __restrict__ outp,
                                         unsigned& off, float& v, float& a,
                                         float& snum, float& th) {
    const float* rb = ring + (slot << 10) + lane;
    float ib[16];
#pragma unroll
    for (int j = 0; j < 16; ++j) ib[j] = rb[j << 6];   // 2 lanes/bank: free
#pragma unroll
    for (int j = 0; j < 16; ++j) {
        const float It = ib[j];
        v = __fmaf_rn(v, kVD, It);                     // leak + input
        const bool fire = (v >= th);
        const float s = fire ? 1.0f : 0.0f;
        snum += s;                                     // exact int accum
        if (STORE) {
            const float val = (W == 0) ? s : (W == 1) ? snum : v;
            __builtin_nontemporal_store(val, outp + off);
        }
        v = fire ? -0.5f : v;                          // exact reset
        a = __fmaf_rn(a, kAD, s);
        th = __fmaf_rn(1.5f, a, 1.5f);
        off += kK;
    }
}

template <int W, int PAR>
__device__ __forceinline__ void run_consumer(const float* __restrict__ ring,
                                             const int lane,
                                             float* __restrict__ outp) {
    float v = 0.0f, a = 0.0f, snum = 0.0f, th = 1.5f;
    unsigned off = 0;
#pragma unroll 1
    for (int p = 0; p < 32; ++p) {
        const int s0 = (p & 3) << 1;                   // slot of slab 2p
        __builtin_amdgcn_s_barrier();
        asm volatile("" ::: "memory");                 // pin ds_reads after
        eat_slab<W, PAR == 0>(ring, s0,     lane, outp, off, v, a, snum, th);
        eat_slab<W, PAR == 1>(ring, s0 + 1, lane, outp, off, v, a, snum, th);
    }
}

__global__ __launch_bounds__(448) void multilif_fwd(
        const float* __restrict__ I, float* __restrict__ out) {
    __shared__ __align__(16) float ring[kRing * kSlabFloats];   // 32 KB
    const int lane = (int)threadIdx.x & 63;
    const int w = (int)threadIdx.x >> 6;             // 0 = loader, 1..6 cons.
    const int wb0 = (int)blockIdx.x * 64;            // first chain of group
    const size_t cb = (size_t)(wb0 >> 9) * ((size_t)kL * kK)
                    + (size_t)(wb0 & (kK - 1));

    if (w == 0) {
        // per-lane source offset matching DMA LDS layout (lane*16B):
        // t_off = lane>>4 (0..3), k_off = (lane&15)*4
        const float* gsrc = I + cb + (size_t)(lane >> 4) * kK
                          + (size_t)((lane & 15) << 2);
        run_loader(gsrc, ring);
        return;
    }
    const int cw = w - 1;                            // 0..5
    float* outp = out + (size_t)(cw >> 1) * kN + cb + (size_t)lane;
    switch (cw) {
        case 0: run_consumer<0, 0>(ring, lane, outp); break;  // spikes even
        case 1: run_consumer<0, 1>(ring, lane, outp); break;  // spikes odd
        case 2: run_consumer<1, 0>(ring, lane, outp); break;  // series even
        case 3: run_consumer<1, 1>(ring, lane, outp); break;  // series odd
        case 4: run_consumer<2, 0>(ring, lane, outp); break;  // v_seq even
        default: run_consumer<2, 1>(ring, lane, outp); break; // v_seq odd
    }
}

extern "C" void kernel_launch(void* const* d_in, const int* in_sizes, int n_in,
                              void* d_out, int out_size, void* d_ws, size_t ws_size,
                              hipStream_t stream) {
    const float* I = (const float*)d_in[0];
    float* out = (float*)d_out;
    // 256 chain-groups x (1 loader + 6 consumer) waves = 256 blocks x 448 thr.
    dim3 grid((32 * kK) / 64), block(448);
    hipLaunchKernelGGL(multilif_fwd, grid, block, 0, stream, I, out);
}

// Round 6
// 42.030 us; speedup vs baseline: 1.3898x; 1.0054x over previous
//
#include <hip/hip_runtime.h>

// MultiLIF forward: B=32, L=1024, K=512. 16384 chains (b,k), serial over t.
// Outputs concat: [spikes | series | v_seq], each B*L*K f32.
//
// Numerics (validated r1-r6): pass = zero spike flips + small v drift.
// Fused updates: v<-fma(v,.95,I), a<-fma(a,.99,s), th<-fma(1.5,a,1.5);
// s == s_hard exactly; reset = (fire ? -0.5 : v); snum exact int accum.
//
// r12 = r11 (best known, 42.3us) with sync frequency halved AGAIN:
// barrier every 4 slabs (16 barriers) instead of every 2 (32). r11
// proved barrier cadence is the lever: 64->32 barriers bought 4.45us
// (~139ns per eliminated barrier: 7-wave lockstep skew + lost overlap).
// Period = 4 slabs = ping-pong halves of the 8-slab ring.
//
// Structure (per 64-chain group, 1 block, 448 thr):
//   wave 0   = loader: global_load_lds dwordx4 into 32KB LDS ring (8
//              slabs x 16 steps x 64 chains x 4B). Prologue issues slabs
//              0..3 (16 DMA); period p: vmcnt(0) [batch p-1 was issued a
//              full ~2.6us earlier - landed, zero stall; stream is
//              loads-only so nothing else drains] -> s_barrier -> issue
//              slabs 4p+4..4p+7 into the half consumers vacated in
//              period p-1. Max 16 outstanding < 63 cap. Zero register
//              footprint (r9: reg staging spilled -> 58us).
//   waves1-6 = consumers (3 streams x 2 store-parities, template-
//              specialized straightline slabs -- r7: runtime store
//              branches force conservative vmcnt joins): ds_read_b32
//              from ring (2 lanes/bank = free), nontemporal stores
//              NEVER vmcnt-waited (r7/r8: consume-waits in a mixed
//              vmcnt stream drain all older stores).
// Sync = raw s_barrier (NOT __syncthreads: emits vmcnt(0) in consumer
// waves, would drain their store queue). asm memory clobber pins LDS
// ops on the correct side of each barrier.
// Ring math: period p consumers read slots (p&1)*4+{0..3} (= slabs
// 4p..4p+3); loader fills the other half (slabs 4p+4..4p+7), which was
// consumed in period p-1. No WAR. 16 periods x 4 slabs = 64 slabs.

namespace {
constexpr int kL = 1024;
constexpr int kK = 512;
constexpr size_t kN = (size_t)32 * kL * kK;      // per-output elements
constexpr float kVD = 1.0f - 1.0f / 20.0f;       // 0.95f
constexpr float kAD = 1.0f - 1.0f / 100.0f;      // 0.99f
constexpr int kSlabSteps = 16;                   // t-steps per slab
constexpr int kRing = 8;                         // slabs resident in LDS
constexpr int kSlabFloats = kSlabSteps * 64;     // 1024 floats = 4KB
}

// One DMA instruction: 64 lanes x 16B -> 1KB contiguous LDS at uniform base.
__device__ __forceinline__ void gload_lds16(const float* g, float* l) {
    __builtin_amdgcn_global_load_lds(
        (const __attribute__((address_space(1))) void*)g,
        (__attribute__((address_space(3))) void*)l, 16, 0, 0);
}

// Issue one slab (4KB = 4 DMA ops). gsrc already carries the per-lane
// offset (t_off = lane>>4, k_off = (lane&15)*4) matching the DMA's
// fixed LDS layout (base + lane*16B), so LDS ends up linear [t][k].
__device__ __forceinline__ void issue_dma(const float* __restrict__ gsrc,
                                          float* __restrict__ ring,
                                          const int slab, const int slot) {
    const float* gs = gsrc + (size_t)(slab * kSlabSteps) * kK;
    float* ls = ring + (slot << 10);
#pragma unroll
    for (int q = 0; q < 4; ++q)
        gload_lds16(gs + (size_t)(q * 4) * kK, ls + (q << 8));
}

__device__ __forceinline__ void run_loader(const float* __restrict__ gsrc,
                                           float* __restrict__ ring) {
    // prologue: issue slabs 0..3 (slots 0..3) -> 16 loads in flight
#pragma unroll
    for (int s = 0; s < 4; ++s) issue_dma(gsrc, ring, s, s);
    // main periods 0..14: drain previous batch, release consumers into
    // slabs 4p..4p+3, refill the vacated half with slabs 4p+4..4p+7.
#pragma unroll 1
    for (int p = 0; p < 15; ++p) {
        asm volatile("s_waitcnt vmcnt(0)" ::: "memory");
        __builtin_amdgcn_s_barrier();
        asm volatile("" ::: "memory");
        const int s0 = 4 * p + 4;
        issue_dma(gsrc, ring, s0 + 0, (s0 + 0) & 7);
        issue_dma(gsrc, ring, s0 + 1, (s0 + 1) & 7);
        issue_dma(gsrc, ring, s0 + 2, (s0 + 2) & 7);
        issue_dma(gsrc, ring, s0 + 3, (s0 + 3) & 7);
    }
    // final period 15: slabs 60..63 ready, nothing left to issue.
    asm volatile("s_waitcnt vmcnt(0)" ::: "memory");
    __builtin_amdgcn_s_barrier();
}

// ---- consumer: one slab, no barrier inside. W: 0=spikes,1=series,2=v. ----
template <int W, bool STORE>
__device__ __forceinline__ void eat_slab(const float* __restrict__ ring,
                                         const int slot, const int lane,
                                         float* __restrict__ outp,
                                         unsigned& off, float& v, float& a,
                                         float& snum, float& th) {
    const float* rb = ring + (slot << 10) + lane;
    float ib[16];
#pragma unroll
    for (int j = 0; j < 16; ++j) ib[j] = rb[j << 6];   // 2 lanes/bank: free
#pragma unroll
    for (int j = 0; j < 16; ++j) {
        const float It = ib[j];
        v = __fmaf_rn(v, kVD, It);                     // leak + input
        const bool fire = (v >= th);
        const float s = fire ? 1.0f : 0.0f;
        snum += s;                                     // exact int accum
        if (STORE) {
            const float val = (W == 0) ? s : (W == 1) ? snum : v;
            __builtin_nontemporal_store(val, outp + off);
        }
        v = fire ? -0.5f : v;                          // exact reset
        a = __fmaf_rn(a, kAD, s);
        th = __fmaf_rn(1.5f, a, 1.5f);
        off += kK;
    }
}

// PAR selects which slabs of each 4-slab period this wave stores
// ({0,2} for PAR=0, {1,3} for PAR=1).
template <int W, int PAR>
__device__ __forceinline__ void run_consumer(const float* __restrict__ ring,
                                             const int lane,
                                             float* __restrict__ outp) {
    float v = 0.0f, a = 0.0f, snum = 0.0f, th = 1.5f;
    unsigned off = 0;
#pragma unroll 1
    for (int p = 0; p < 16; ++p) {
        const int base = (p & 1) << 2;                 // slot of slab 4p
        __builtin_amdgcn_s_barrier();
        asm volatile("" ::: "memory");                 // pin ds_reads after
        eat_slab<W, PAR == 0>(ring, base + 0, lane, outp, off, v, a, snum, th);
        eat_slab<W, PAR == 1>(ring, base + 1, lane, outp, off, v, a, snum, th);
        eat_slab<W, PAR == 0>(ring, base + 2, lane, outp, off, v, a, snum, th);
        eat_slab<W, PAR == 1>(ring, base + 3, lane, outp, off, v, a, snum, th);
    }
}

__global__ __launch_bounds__(448) void multilif_fwd(
        const float* __restrict__ I, float* __restrict__ out) {
    __shared__ __align__(16) float ring[kRing * kSlabFloats];   // 32 KB
    const int lane = (int)threadIdx.x & 63;
    const int w = (int)threadIdx.x >> 6;             // 0 = loader, 1..6 cons.
    const int wb0 = (int)blockIdx.x * 64;            // first chain of group
    const size_t cb = (size_t)(wb0 >> 9) * ((size_t)kL * kK)
                    + (size_t)(wb0 & (kK - 1));

    if (w == 0) {
        // per-lane source offset matching DMA LDS layout (lane*16B):
        // t_off = lane>>4 (0..3), k_off = (lane&15)*4
        const float* gsrc = I + cb + (size_t)(lane >> 4) * kK
                          + (size_t)((lane & 15) << 2);
        run_loader(gsrc, ring);
        return;
    }
    const int cw = w - 1;                            // 0..5
    float* outp = out + (size_t)(cw >> 1) * kN + cb + (size_t)lane;
    switch (cw) {
        case 0: run_consumer<0, 0>(ring, lane, outp); break;  // spikes even
        case 1: run_consumer<0, 1>(ring, lane, outp); break;  // spikes odd
        case 2: run_consumer<1, 0>(ring, lane, outp); break;  // series even
        case 3: run_consumer<1, 1>(ring, lane, outp); break;  // series odd
        case 4: run_consumer<2, 0>(ring, lane, outp); break;  // v_seq even
        default: run_consumer<2, 1>(ring, lane, outp); break; // v_seq odd
    }
}

extern "C" void kernel_launch(void* const* d_in, const int* in_sizes, int n_in,
                              void* d_out, int out_size, void* d_ws, size_t ws_size,
                              hipStream_t stream) {
    const float* I = (const float*)d_in[0];
    float* out = (float*)d_out;
    // 256 chain-groups x (1 loader + 6 consumer) waves = 256 blocks x 448 thr.
    dim3 grid((32 * kK) / 64), block(448);
    hipLaunchKernelGGL(multilif_fwd, grid, block, 0, stream, I, out);
}